// Round 3
// baseline (930.993 us; speedup 1.0000x reference)
//
#include <hip/hip_runtime.h>

// Problem constants (fixed by setup_inputs)
#define B_   16
#define N_   4096
#define DF   1024   // D_FEAT (= key rows of W)
#define DQ   1024   // D_Q
#define DA   512    // D_ATTN
#define NDT  8      // number of d-tiles in main GEMM (DA / BN)
#define NS   32     // n-splits for context partial sums

typedef __attribute__((ext_vector_type(8))) short short8v;   // 8 bf16
typedef __attribute__((ext_vector_type(4))) float f32x4;

static __device__ __forceinline__ unsigned short f2bf(float x) {
    return __builtin_bit_cast(unsigned short, (__bf16)x);  // RNE, compiler packs pairs into v_cvt_pk_bf16_f32
}

// ---------------------------------------------------------------------------
// Kernel 1: transpose+convert W[0:1024,:] (key part) into Wt[gate][d][k] bf16
// grid (32 k-tiles, 16 d-tiles, 2 gates), block 256
// ---------------------------------------------------------------------------
__global__ void wconv_kernel(const float* __restrict__ W1, const float* __restrict__ W2,
                             unsigned short* __restrict__ Wt) {
    __shared__ float tile[32][33];
    int kt = blockIdx.x * 32, dt = blockIdx.y * 32, g = blockIdx.z;
    const float* W = g ? W2 : W1;
    int tx = threadIdx.x & 31, ty = threadIdx.x >> 5;  // ty 0..7
#pragma unroll
    for (int i = 0; i < 4; ++i) {
        int r = ty + i * 8;
        tile[r][tx] = W[(size_t)(kt + r) * DA + dt + tx];
    }
    __syncthreads();
#pragma unroll
    for (int i = 0; i < 4; ++i) {
        int r = ty + i * 8;  // d within tile
        Wt[((size_t)g * DA + dt + r) * DF + kt + tx] = f2bf(tile[tx][r]);
    }
}

// ---------------------------------------------------------------------------
// Kernel 2: qproj[g][b][d] = bias_g[d] + sum_k q[b][k] * Wg[1024+k][d]
// grid (2 dchunks, 16 b, 2 gates), block 256
// ---------------------------------------------------------------------------
__global__ void qproj_kernel(const float* __restrict__ q,
                             const float* __restrict__ W1, const float* __restrict__ b1,
                             const float* __restrict__ W2, const float* __restrict__ b2,
                             float* __restrict__ qp) {
    int d = blockIdx.x * 256 + threadIdx.x;
    int b = blockIdx.y, g = blockIdx.z;
    const float* W = g ? W2 : W1;
    const float* bias = g ? b2 : b1;
    const float* qb = q + (size_t)b * DQ;
    float acc = bias[d];
    for (int k = 0; k < DQ; k += 4) {
        float4 q4 = *(const float4*)(qb + k);
        acc += q4.x * W[(size_t)(DF + k + 0) * DA + d];
        acc += q4.y * W[(size_t)(DF + k + 1) * DA + d];
        acc += q4.z * W[(size_t)(DF + k + 2) * DA + d];
        acc += q4.w * W[(size_t)(DF + k + 3) * DA + d];
    }
    qp[((size_t)g * B_ + b) * DA + d] = acc;
}

// ---------------------------------------------------------------------------
// Kernel 3: main fused GEMM + gated-tanh + score partial reduce.
// C1 = key_tile @ W1k, C2 = key_tile @ W2k (shared A tile), then
// score_part[b][n][dt] = sum_{d in tile} tanh(C1+qp1)*sigmoid(C2+qp2)*w_a[d]
// Tiles: BM=128 rows, BN=64 cols, BK=64. 256 threads = 4 waves,
// wave w owns rows [w*32, w*32+32), all 64 cols. 16x16x32 bf16 MFMA.
// grid 4096 blocks, XCD-swizzled so the 8 dt-blocks of a row-tile share an XCD.
// ---------------------------------------------------------------------------
#define BM 128
#define BN 64
#define BK 64
#define BKP 72   // padded k-stride (bf16 elems): 144B rows -> banks rotate by 4

__global__ __launch_bounds__(256, 2) void gemm_score_kernel(
        const float* __restrict__ key, const unsigned short* __restrict__ Wt,
        const float* __restrict__ qp, const float* __restrict__ w_a,
        float* __restrict__ scores_part) {
    __shared__ unsigned short Alds[BM * BKP];      // 18432 B
    __shared__ unsigned short Blds[2 * BN * BKP];  // 18432 B

    // XCD-aware decode: p%8 = xcd; the 8 dt-blocks of group gidx are all ≡ same xcd (mod 8)
    int p = blockIdx.x;
    int xcd = p & 7;
    int q = p >> 3;            // 0..511
    int gidx = xcd * 64 + (q >> 3);   // 0..511  (b, mt) group
    int dt = q & 7;
    int b = gidx >> 5;         // 0..15
    int mt = gidx & 31;        // 0..31

    int t = threadIdx.x;
    int w = t >> 6;            // wave 0..3
    int l = t & 63;            // lane
    int jj = l & 15;           // frag col / frag row selector
    int g2 = l >> 4;           // k-group / row-group

    const float* Abase = key + ((size_t)b * N_ + (size_t)mt * BM) * DF;
    const unsigned short* Bbase = Wt + (size_t)dt * BN * DF;  // + gate*DA*DF

    f32x4 acc[2][2][4];  // [gate][mi][fj]
#pragma unroll
    for (int g = 0; g < 2; ++g)
#pragma unroll
        for (int mi = 0; mi < 2; ++mi)
#pragma unroll
            for (int fj = 0; fj < 4; ++fj) acc[g][mi][fj] = (f32x4)0.f;

    int tr = t >> 4;            // 0..15 (row group for A staging)
    int tc = (t & 15) * 4;      // f32 col for A staging

    for (int kt = 0; kt < DF / BK; ++kt) {
        int k0 = kt * BK;
        // ---- stage A: 128x64 fp32 -> bf16 ----
#pragma unroll
        for (int j = 0; j < 8; ++j) {
            int row = j * 16 + tr;
            float4 v = *(const float4*)(Abase + (size_t)row * DF + k0 + tc);
            ushort4 h;
            h.x = f2bf(v.x); h.y = f2bf(v.y); h.z = f2bf(v.z); h.w = f2bf(v.w);
            *(ushort4*)(&Alds[row * BKP + tc]) = h;
        }
        // ---- stage B: 2 gates x 64 cols x 64 k bf16 ----
#pragma unroll
        for (int j = 0; j < 4; ++j) {
            int c = t + 256 * j;          // chunk of 8 bf16
            int gate = c >> 9;
            int rem = c & 511;
            int col = rem >> 3;
            int kc = (rem & 7) * 8;
            uint4 vv = *(const uint4*)(Bbase + ((size_t)gate * DA + col) * DF + k0 + kc);
            *(uint4*)(&Blds[(gate * BN + col) * BKP + kc]) = vv;
        }
        __syncthreads();
        // ---- MFMA ----
#pragma unroll
        for (int kk = 0; kk < 2; ++kk) {
            int koff = kk * 32 + g2 * 8;
            short8v a0 = *(const short8v*)(&Alds[(w * 32 + 0 + jj) * BKP + koff]);
            short8v a1 = *(const short8v*)(&Alds[(w * 32 + 16 + jj) * BKP + koff]);
#pragma unroll
            for (int fj = 0; fj < 4; ++fj) {
                short8v b0 = *(const short8v*)(&Blds[(0 * BN + fj * 16 + jj) * BKP + koff]);
                short8v b1 = *(const short8v*)(&Blds[(1 * BN + fj * 16 + jj) * BKP + koff]);
                acc[0][0][fj] = __builtin_amdgcn_mfma_f32_16x16x32_bf16(a0, b0, acc[0][0][fj], 0, 0, 0);
                acc[0][1][fj] = __builtin_amdgcn_mfma_f32_16x16x32_bf16(a1, b0, acc[0][1][fj], 0, 0, 0);
                acc[1][0][fj] = __builtin_amdgcn_mfma_f32_16x16x32_bf16(a0, b1, acc[1][0][fj], 0, 0, 0);
                acc[1][1][fj] = __builtin_amdgcn_mfma_f32_16x16x32_bf16(a1, b1, acc[1][1][fj], 0, 0, 0);
            }
        }
        __syncthreads();
    }

    // ---- epilogue: gate + weighted col-reduce -> scores_part[b][n][dt] ----
    // C/D frag: col = lane&15 (jj), row = (lane>>4)*4 + reg  [m89-verified]
    const float* qp1b = qp + (size_t)b * DA;             // gate 0
    const float* qp2b = qp + ((size_t)B_ + b) * DA;      // gate 1
#pragma unroll
    for (int mi = 0; mi < 2; ++mi) {
        float s0 = 0.f, s1 = 0.f, s2 = 0.f, s3 = 0.f;
#pragma unroll
        for (int fj = 0; fj < 4; ++fj) {
            int col = dt * BN + fj * 16 + jj;
            float q1 = qp1b[col];
            float q2 = qp2b[col];
            float wa = w_a[col];
#pragma unroll
            for (int r = 0; r < 4; ++r) {
                float p1 = acc[0][mi][fj][r] + q1;
                float p2 = acc[1][mi][fj][r] + q2;
                float ax = fabsf(p1);
                float e = __expf(-2.f * ax);
                float th = __builtin_copysignf((1.f - e) / (1.f + e), p1);
                float sg = 1.f / (1.f + __expf(-p2));
                float h = th * sg * wa;
                if (r == 0) s0 += h; else if (r == 1) s1 += h; else if (r == 2) s2 += h; else s3 += h;
            }
        }
#pragma unroll
        for (int off = 1; off < 16; off <<= 1) {
            s0 += __shfl_xor(s0, off);
            s1 += __shfl_xor(s1, off);
            s2 += __shfl_xor(s2, off);
            s3 += __shfl_xor(s3, off);
        }
        float v = (jj == 0) ? s0 : (jj == 1) ? s1 : (jj == 2) ? s2 : s3;
        if (jj < 4) {
            int row = w * 32 + mi * 16 + g2 * 4 + jj;
            scores_part[((size_t)b * N_ + (size_t)mt * BM + row) * NDT + dt] = v;
        }
    }
}

// ---------------------------------------------------------------------------
// Kernel 4: per-batch masked softmax. grid 16, block 256 (each thread 16 rows)
// ---------------------------------------------------------------------------
__global__ void softmax_kernel(const float* __restrict__ scores_part,
                               const int* __restrict__ mask,
                               float* __restrict__ attn_out) {
    int b = blockIdx.x;
    int t = threadIdx.x;
    __shared__ float wred[4];

    float vals[16];
    float mx = -3.0e38f;
#pragma unroll
    for (int i = 0; i < 16; ++i) {
        int n = t + 256 * i;
        const float4* sp = (const float4*)(scores_part + ((size_t)b * N_ + n) * NDT);
        float4 u = sp[0], v = sp[1];
        float s = ((u.x + u.y) + (u.z + u.w)) + ((v.x + v.y) + (v.z + v.w));
        if (mask[(size_t)b * N_ + n] == 0) s = -1e18f;
        vals[i] = s;
        mx = fmaxf(mx, s);
    }
#pragma unroll
    for (int off = 32; off >= 1; off >>= 1) mx = fmaxf(mx, __shfl_xor(mx, off));
    if ((t & 63) == 0) wred[t >> 6] = mx;
    __syncthreads();
    mx = fmaxf(fmaxf(wred[0], wred[1]), fmaxf(wred[2], wred[3]));
    __syncthreads();

    float sum = 0.f;
#pragma unroll
    for (int i = 0; i < 16; ++i) {
        float e = __expf(vals[i] - mx);
        vals[i] = e;
        sum += e;
    }
#pragma unroll
    for (int off = 32; off >= 1; off >>= 1) sum += __shfl_xor(sum, off);
    if ((t & 63) == 0) wred[t >> 6] = sum;
    __syncthreads();
    sum = ((wred[0] + wred[1]) + (wred[2] + wred[3]));
    float inv = 1.f / sum;
#pragma unroll
    for (int i = 0; i < 16; ++i) attn_out[(size_t)b * N_ + t + 256 * i] = vals[i] * inv;
}

// ---------------------------------------------------------------------------
// Kernel 5: context partials: ctx_part[b][ns][df] = sum_{n in chunk} attn*value
// grid (NS, 16), block 256, each thread one float4 of DF
// ---------------------------------------------------------------------------
__global__ void ctx_part_kernel(const float* __restrict__ attn,
                                const float* __restrict__ value,
                                float* __restrict__ ctx_part) {
    int ns = blockIdx.x, b = blockIdx.y, t = threadIdx.x;
    const int NCH = N_ / NS;  // 128
    const float* vb = value + ((size_t)b * N_ + (size_t)ns * NCH) * DF + t * 4;
    const float* ab = attn + (size_t)b * N_ + ns * NCH;
    float4 acc = {0.f, 0.f, 0.f, 0.f};
#pragma unroll 4
    for (int i = 0; i < NCH; ++i) {
        float a = ab[i];
        float4 v = *(const float4*)(vb + (size_t)i * DF);
        acc.x += a * v.x; acc.y += a * v.y; acc.z += a * v.z; acc.w += a * v.w;
    }
    *(float4*)(ctx_part + ((size_t)b * NS + ns) * DF + t * 4) = acc;
}

// ---------------------------------------------------------------------------
// Kernel 6: reduce partials -> d_out context. grid 16, block 256 (float4 each)
// ---------------------------------------------------------------------------
__global__ void ctx_reduce_kernel(const float* __restrict__ ctx_part,
                                  float* __restrict__ ctx_out) {
    int b = blockIdx.x, t = threadIdx.x;
    float4 acc = {0.f, 0.f, 0.f, 0.f};
#pragma unroll
    for (int j = 0; j < NS; ++j) {
        float4 v = *(const float4*)(ctx_part + ((size_t)b * NS + j) * DF + t * 4);
        acc.x += v.x; acc.y += v.y; acc.z += v.z; acc.w += v.w;
    }
    *(float4*)(ctx_out + (size_t)b * DF + t * 4) = acc;
}

// ---------------------------------------------------------------------------
extern "C" void kernel_launch(void* const* d_in, const int* in_sizes, int n_in,
                              void* d_out, int out_size, void* d_ws, size_t ws_size,
                              hipStream_t stream) {
    const float* query = (const float*)d_in[0];
    const float* key   = (const float*)d_in[1];
    const float* value = (const float*)d_in[2];
    const int*   mask  = (const int*)d_in[3];
    const float* W1    = (const float*)d_in[4];
    const float* b1    = (const float*)d_in[5];
    const float* W2    = (const float*)d_in[6];
    const float* b2    = (const float*)d_in[7];
    const float* w_a   = (const float*)d_in[8];

    float* attn_out = (float*)d_out;                 // [16,4096]
    float* ctx_out  = (float*)d_out + (size_t)B_ * N_;  // [16,1024]

    char* ws = (char*)d_ws;
    unsigned short* Wt = (unsigned short*)ws;                         // 2*512*1024*2 = 2 MB
    size_t off = (size_t)2 * DA * DF * sizeof(unsigned short);
    float* qp = (float*)(ws + off);                                   // 2*16*512*4 = 64 KB
    off += (size_t)2 * B_ * DA * sizeof(float);
    float* scores_part = (float*)(ws + off);                          // 16*4096*8*4 = 2 MB
    off += (size_t)B_ * N_ * NDT * sizeof(float);
    float* ctx_part = (float*)(ws + off);                             // 16*32*1024*4 = 2 MB
    off += (size_t)B_ * NS * DF * sizeof(float);

    wconv_kernel<<<dim3(DF / 32, DA / 32, 2), 256, 0, stream>>>(W1, W2, Wt);
    qproj_kernel<<<dim3(DA / 256, B_, 2), 256, 0, stream>>>(query, W1, b1, W2, b2, qp);
    gemm_score_kernel<<<dim3(B_ * (N_ / BM) * NDT), 256, 0, stream>>>(key, Wt, qp, w_a, scores_part);
    softmax_kernel<<<dim3(B_), 256, 0, stream>>>(scores_part, mask, attn_out);
    ctx_part_kernel<<<dim3(NS, B_), 256, 0, stream>>>(attn_out, value, ctx_part);
    ctx_reduce_kernel<<<dim3(B_), 256, 0, stream>>>(ctx_part, ctx_out);
}

// Round 4
// 700.979 us; speedup vs baseline: 1.3281x; 1.3281x over previous
//
#include <hip/hip_runtime.h>

// Problem constants (fixed by setup_inputs)
#define B_   16
#define N_   4096
#define DF   1024   // D_FEAT
#define DQ   1024   // D_Q
#define DA   512    // D_ATTN
#define NDT  8      // score partials per row
#define NS   32     // n-splits for context partial sums

typedef __attribute__((ext_vector_type(8))) short short8v;   // 8 bf16
typedef __attribute__((ext_vector_type(4))) float f32x4;

static __device__ __forceinline__ unsigned short f2bf(float x) {
    return __builtin_bit_cast(unsigned short, (__bf16)x);
}

// async global->LDS, 16B per lane, LDS dest = wave-uniform base + lane*16
static __device__ __forceinline__ void gload_lds16(const void* g, void* l) {
    __builtin_amdgcn_global_load_lds((const __attribute__((address_space(1))) unsigned int*)g,
                                     (__attribute__((address_space(3))) unsigned int*)l, 16, 0, 0);
}

// ---------------------------------------------------------------------------
// Kernel 1: W key-rows -> bf16 "LDS image" layout, XOR-swizzle baked in.
// WtImg[(dt*16+ktL)*2+g][col][physslot][e] ; physslot = (kin>>3) ^ (col&7)
// grid (32 k-tiles, 16 d-tiles, 2 gates), block 256
// ---------------------------------------------------------------------------
__global__ void wconv_kernel(const float* __restrict__ W1, const float* __restrict__ W2,
                             unsigned short* __restrict__ WtImg) {
    __shared__ float tile[32][33];
    int kt = blockIdx.x * 32, dt0 = blockIdx.y * 32, g = blockIdx.z;
    const float* W = g ? W2 : W1;
    int tx = threadIdx.x & 31, ty = threadIdx.x >> 5;  // ty 0..7
#pragma unroll
    for (int i = 0; i < 4; ++i) {
        int r = ty + i * 8;
        tile[r][tx] = W[(size_t)(kt + r) * DA + dt0 + tx];
    }
    __syncthreads();
#pragma unroll
    for (int i = 0; i < 4; ++i) {
        int r = ty + i * 8;                 // d within tile
        int d = dt0 + r, k = kt + tx;       // value = W[k][d]
        int dtI = d >> 6, col = d & 63, ktL = k >> 6, kin = k & 63;
        int slot = (kin >> 3) ^ (col & 7), e = kin & 7;
        size_t off = ((((size_t)dtI * 16 + ktL) * 2 + g) * 64 + col) * 64 + slot * 8 + e;
        WtImg[off] = f2bf(tile[tx][r]);
    }
}

// ---------------------------------------------------------------------------
// Kernel 2: qproj[g][b][d] = bias_g[d] + sum_k q[b][k] * Wg[1024+k][d]
// ---------------------------------------------------------------------------
__global__ void qproj_kernel(const float* __restrict__ q,
                             const float* __restrict__ W1, const float* __restrict__ b1,
                             const float* __restrict__ W2, const float* __restrict__ b2,
                             float* __restrict__ qp) {
    int d = blockIdx.x * 256 + threadIdx.x;
    int b = blockIdx.y, g = blockIdx.z;
    const float* W = g ? W2 : W1;
    const float* bias = g ? b2 : b1;
    const float* qb = q + (size_t)b * DQ;
    float acc = bias[d];
    for (int k = 0; k < DQ; k += 4) {
        float4 q4 = *(const float4*)(qb + k);
        acc += q4.x * W[(size_t)(DF + k + 0) * DA + d];
        acc += q4.y * W[(size_t)(DF + k + 1) * DA + d];
        acc += q4.z * W[(size_t)(DF + k + 2) * DA + d];
        acc += q4.w * W[(size_t)(DF + k + 3) * DA + d];
    }
    qp[((size_t)g * B_ + b) * DA + d] = acc;
}

// ---------------------------------------------------------------------------
// Kernel 3: fused GEMM + gated-tanh + score reduce. m97-shaped:
// BM=128 rows, per-gate 64 cols (dt tile), BK=64, 4 waves of 64x(32x2g).
// A: reg-prefetch fp32->bf16 -> XOR-swz LDS. B: gload_lds from pre-swz WtImg,
// double-buffered. Raw barriers + lgkmcnt(0): prefetch stays in flight.
// ---------------------------------------------------------------------------
#define BM 128
#define BK 64

__global__ __launch_bounds__(256, 3) void gemm_score_kernel(
        const float* __restrict__ key, const unsigned short* __restrict__ WtImg,
        const float* __restrict__ qp, const float* __restrict__ w_a,
        float* __restrict__ scores_part) {
    __shared__ unsigned short Alds[BM * 64];          // 16 KB, 128B rows, XOR-swz
    __shared__ unsigned short Blds[2][2 * 64 * 64];   // 2 x 16 KB double buffer
    __shared__ float sred[BM][2];

    // XCD-aware decode (bijective: 4096 = 8*512)
    int p = blockIdx.x;
    int xcd = p & 7;
    int q = p >> 3;                    // 0..511
    int gidx = xcd * 64 + (q >> 3);    // (b, mt) group
    int dt = q & 7;
    int b = gidx >> 5;
    int mt = gidx & 31;

    int t = threadIdx.x;
    int w = t >> 6, l = t & 63;
    int jj = l & 15, g2 = l >> 4;
    int wr = (w >> 1) * 64;            // wave row base
    int wc = (w & 1) * 32;             // wave col base (per gate)

    const float* Abase = key + ((size_t)b * N_ + (size_t)mt * BM) * DF;
    const unsigned short* Bsrc = WtImg + (size_t)dt * 16 * 8192;  // 8192 ushorts per kt

    f32x4 acc[2][4][2];  // [gate][mi][fc]
#pragma unroll
    for (int g = 0; g < 2; ++g)
#pragma unroll
        for (int mi = 0; mi < 4; ++mi)
#pragma unroll
            for (int fc = 0; fc < 2; ++fc) acc[g][mi][fc] = (f32x4)0.f;

    int tr = t >> 4;                  // 0..15: A-stage row group
    int tcf = (t & 15) * 4;           // f32 col within BK
    int aslot = (t & 15) >> 1;        // logical 16B slot
    int ahalf = (t & 1) * 4;          // ushort offset within slot

    float4 areg[8];

    // ---- prologue: issue B(0) + A(0) ----
#pragma unroll
    for (int i = 0; i < 4; ++i) {
        int c = w * 4 + i;
        gload_lds16(Bsrc + (size_t)c * 512 + l * 8, (char*)&Blds[0][0] + c * 1024);
    }
#pragma unroll
    for (int j = 0; j < 8; ++j)
        areg[j] = *(const float4*)(Abase + (size_t)(j * 16 + tr) * DF + tcf);

    for (int kt = 0; kt < DF / BK; ++kt) {
        int cur = kt & 1;
        // (1) cvt + write A(kt)  [implicit vmcnt(0): waits A(kt), hence B(kt) too]
#pragma unroll
        for (int j = 0; j < 8; ++j) {
            int row = j * 16 + tr;
            ushort4 h;
            h.x = f2bf(areg[j].x); h.y = f2bf(areg[j].y);
            h.z = f2bf(areg[j].z); h.w = f2bf(areg[j].w);
            *(ushort4*)(&Alds[row * 64 + ((aslot ^ (tr & 7)) * 8) + ahalf]) = h;
        }
        // (2) issue next tile's loads -- stay in flight across MFMA phase
        if (kt < DF / BK - 1) {
            const unsigned short* src = Bsrc + (size_t)(kt + 1) * 8192;
#pragma unroll
            for (int i = 0; i < 4; ++i) {
                int c = w * 4 + i;
                gload_lds16(src + (size_t)c * 512 + l * 8, (char*)&Blds[cur ^ 1][0] + c * 1024);
            }
            int k0 = (kt + 1) * BK;
#pragma unroll
            for (int j = 0; j < 8; ++j)
                areg[j] = *(const float4*)(Abase + (size_t)(j * 16 + tr) * DF + k0 + tcf);
        }
        // (3) A-writes visible; raw barrier does NOT drain vmcnt
        asm volatile("s_waitcnt lgkmcnt(0)" ::: "memory");
        __builtin_amdgcn_s_barrier();
        __builtin_amdgcn_sched_barrier(0);
        // (4) MFMA on tile kt
#pragma unroll
        for (int kk = 0; kk < 2; ++kk) {
            short8v af[4], bfr[2][2];
            int ps = ((kk * 4 + g2) ^ (jj & 7)) * 8;   // phys slot offset (ushorts)
#pragma unroll
            for (int mi = 0; mi < 4; ++mi)
                af[mi] = *(const short8v*)(&Alds[(wr + mi * 16 + jj) * 64 + ps]);
#pragma unroll
            for (int g = 0; g < 2; ++g)
#pragma unroll
                for (int fc = 0; fc < 2; ++fc)
                    bfr[g][fc] = *(const short8v*)(&Blds[cur][(g * 64 + wc + fc * 16 + jj) * 64 + ps]);
#pragma unroll
            for (int g = 0; g < 2; ++g)
#pragma unroll
                for (int mi = 0; mi < 4; ++mi)
#pragma unroll
                    for (int fc = 0; fc < 2; ++fc)
                        acc[g][mi][fc] = __builtin_amdgcn_mfma_f32_16x16x32_bf16(
                            af[mi], bfr[g][fc], acc[g][mi][fc], 0, 0, 0);
        }
        // (5) all reads consumed; raw barrier guards LDS reuse
        __builtin_amdgcn_sched_barrier(0);
        __builtin_amdgcn_s_barrier();
    }

    // ---- epilogue: gate + weighted col-reduce ----
    // C/D frag: col = jj, row = g2*4 + r  [m89-verified]
    const float* qp1b = qp + (size_t)b * DA;
    const float* qp2b = qp + ((size_t)B_ + b) * DA;
#pragma unroll
    for (int mi = 0; mi < 4; ++mi) {
        float s0 = 0.f, s1 = 0.f, s2 = 0.f, s3 = 0.f;
#pragma unroll
        for (int fc = 0; fc < 2; ++fc) {
            int col = dt * 64 + wc + fc * 16 + jj;
            float q1 = qp1b[col], q2 = qp2b[col], wa = w_a[col];
#pragma unroll
            for (int r = 0; r < 4; ++r) {
                float p1 = acc[0][mi][fc][r] + q1;
                float p2 = acc[1][mi][fc][r] + q2;
                float ax = fabsf(p1);
                float e = __expf(-2.f * ax);
                float th = __builtin_copysignf((1.f - e) / (1.f + e), p1);
                float sg = 1.f / (1.f + __expf(-p2));
                float h = th * sg * wa;
                if (r == 0) s0 += h; else if (r == 1) s1 += h; else if (r == 2) s2 += h; else s3 += h;
            }
        }
#pragma unroll
        for (int off = 1; off < 16; off <<= 1) {
            s0 += __shfl_xor(s0, off);
            s1 += __shfl_xor(s1, off);
            s2 += __shfl_xor(s2, off);
            s3 += __shfl_xor(s3, off);
        }
        float v = (jj == 0) ? s0 : (jj == 1) ? s1 : (jj == 2) ? s2 : s3;
        if (jj < 4) sred[wr + mi * 16 + g2 * 4 + jj][w & 1] = v;
    }
    __syncthreads();
    if (t < BM) {
        scores_part[((size_t)b * N_ + (size_t)mt * BM + t) * NDT + dt] = sred[t][0] + sred[t][1];
    }
}

// ---------------------------------------------------------------------------
// Kernel 4: per-batch masked softmax. grid 16, block 256
// ---------------------------------------------------------------------------
__global__ void softmax_kernel(const float* __restrict__ scores_part,
                               const int* __restrict__ mask,
                               float* __restrict__ attn_out) {
    int b = blockIdx.x;
    int t = threadIdx.x;
    __shared__ float wred[4];

    float vals[16];
    float mx = -3.0e38f;
#pragma unroll
    for (int i = 0; i < 16; ++i) {
        int n = t + 256 * i;
        const float4* sp = (const float4*)(scores_part + ((size_t)b * N_ + n) * NDT);
        float4 u = sp[0], v = sp[1];
        float s = ((u.x + u.y) + (u.z + u.w)) + ((v.x + v.y) + (v.z + v.w));
        if (mask[(size_t)b * N_ + n] == 0) s = -1e18f;
        vals[i] = s;
        mx = fmaxf(mx, s);
    }
#pragma unroll
    for (int off = 32; off >= 1; off >>= 1) mx = fmaxf(mx, __shfl_xor(mx, off));
    if ((t & 63) == 0) wred[t >> 6] = mx;
    __syncthreads();
    mx = fmaxf(fmaxf(wred[0], wred[1]), fmaxf(wred[2], wred[3]));
    __syncthreads();

    float sum = 0.f;
#pragma unroll
    for (int i = 0; i < 16; ++i) {
        float e = __expf(vals[i] - mx);
        vals[i] = e;
        sum += e;
    }
#pragma unroll
    for (int off = 32; off >= 1; off >>= 1) sum += __shfl_xor(sum, off);
    if ((t & 63) == 0) wred[t >> 6] = sum;
    __syncthreads();
    sum = ((wred[0] + wred[1]) + (wred[2] + wred[3]));
    float inv = 1.f / sum;
#pragma unroll
    for (int i = 0; i < 16; ++i) attn_out[(size_t)b * N_ + t + 256 * i] = vals[i] * inv;
}

// ---------------------------------------------------------------------------
// Kernel 5: context partials
// ---------------------------------------------------------------------------
__global__ void ctx_part_kernel(const float* __restrict__ attn,
                                const float* __restrict__ value,
                                float* __restrict__ ctx_part) {
    int ns = blockIdx.x, b = blockIdx.y, t = threadIdx.x;
    const int NCH = N_ / NS;  // 128
    const float* vb = value + ((size_t)b * N_ + (size_t)ns * NCH) * DF + t * 4;
    const float* ab = attn + (size_t)b * N_ + ns * NCH;
    float4 acc = {0.f, 0.f, 0.f, 0.f};
#pragma unroll 4
    for (int i = 0; i < NCH; ++i) {
        float a = ab[i];
        float4 v = *(const float4*)(vb + (size_t)i * DF);
        acc.x += a * v.x; acc.y += a * v.y; acc.z += a * v.z; acc.w += a * v.w;
    }
    *(float4*)(ctx_part + ((size_t)b * NS + ns) * DF + t * 4) = acc;
}

// ---------------------------------------------------------------------------
// Kernel 6: reduce partials -> context
// ---------------------------------------------------------------------------
__global__ void ctx_reduce_kernel(const float* __restrict__ ctx_part,
                                  float* __restrict__ ctx_out) {
    int b = blockIdx.x, t = threadIdx.x;
    float4 acc = {0.f, 0.f, 0.f, 0.f};
#pragma unroll
    for (int j = 0; j < NS; ++j) {
        float4 v = *(const float4*)(ctx_part + ((size_t)b * NS + j) * DF + t * 4);
        acc.x += v.x; acc.y += v.y; acc.z += v.z; acc.w += v.w;
    }
    *(float4*)(ctx_out + (size_t)b * DF + t * 4) = acc;
}

// ---------------------------------------------------------------------------
extern "C" void kernel_launch(void* const* d_in, const int* in_sizes, int n_in,
                              void* d_out, int out_size, void* d_ws, size_t ws_size,
                              hipStream_t stream) {
    const float* query = (const float*)d_in[0];
    const float* key   = (const float*)d_in[1];
    const float* value = (const float*)d_in[2];
    const int*   mask  = (const int*)d_in[3];
    const float* W1    = (const float*)d_in[4];
    const float* b1    = (const float*)d_in[5];
    const float* W2    = (const float*)d_in[6];
    const float* b2    = (const float*)d_in[7];
    const float* w_a   = (const float*)d_in[8];

    float* attn_out = (float*)d_out;                    // [16,4096]
    float* ctx_out  = (float*)d_out + (size_t)B_ * N_;  // [16,1024]

    char* ws = (char*)d_ws;
    unsigned short* WtImg = (unsigned short*)ws;                      // 2 MB
    size_t off = (size_t)2 * DA * DF * sizeof(unsigned short);
    float* qp = (float*)(ws + off);                                   // 64 KB
    off += (size_t)2 * B_ * DA * sizeof(float);
    float* scores_part = (float*)(ws + off);                          // 2 MB
    off += (size_t)B_ * N_ * NDT * sizeof(float);
    float* ctx_part = (float*)(ws + off);                             // 2 MB
    off += (size_t)B_ * NS * DF * sizeof(float);

    wconv_kernel<<<dim3(DF / 32, DA / 32, 2), 256, 0, stream>>>(W1, W2, WtImg);
    qproj_kernel<<<dim3(DA / 256, B_, 2), 256, 0, stream>>>(query, W1, b1, W2, b2, qp);
    gemm_score_kernel<<<dim3(B_ * (N_ / BM) * NDT), 256, 0, stream>>>(key, WtImg, qp, w_a, scores_part);
    softmax_kernel<<<dim3(B_), 256, 0, stream>>>(scores_part, mask, attn_out);
    ctx_part_kernel<<<dim3(NS, B_), 256, 0, stream>>>(attn_out, value, ctx_part);
    ctx_reduce_kernel<<<dim3(B_), 256, 0, stream>>>(ctx_part, ctx_out);
}

// Round 5
// 667.865 us; speedup vs baseline: 1.3940x; 1.0496x over previous
//
#include <hip/hip_runtime.h>

// Problem constants (fixed by setup_inputs)
#define B_   16
#define N_   4096
#define DF   1024   // D_FEAT
#define DQ   1024   // D_Q
#define DA   512    // D_ATTN
#define NDT  8      // score partials per row
#define NS   32     // n-splits for context partial sums

typedef __attribute__((ext_vector_type(8))) short short8v;   // 8 bf16
typedef __attribute__((ext_vector_type(4))) float f32x4;

static __device__ __forceinline__ unsigned short f2bf(float x) {
    return __builtin_bit_cast(unsigned short, (__bf16)x);
}

// async global->LDS, 16B per lane, LDS dest = wave-uniform base + lane*16
static __device__ __forceinline__ void gload_lds16(const void* g, void* l) {
    __builtin_amdgcn_global_load_lds((const __attribute__((address_space(1))) unsigned int*)g,
                                     (__attribute__((address_space(3))) unsigned int*)l, 16, 0, 0);
}

// ---------------------------------------------------------------------------
// Kernel 1: W key-rows -> bf16 "LDS image" layout, XOR-swizzle baked in.
// WtImg[(dt*16+ktL)*2+g][col][physslot][e] ; physslot = (kin>>3) ^ (col&7)
// grid (32 k-tiles, 16 d-tiles, 2 gates), block 256
// ---------------------------------------------------------------------------
__global__ void wconv_kernel(const float* __restrict__ W1, const float* __restrict__ W2,
                             unsigned short* __restrict__ WtImg) {
    __shared__ float tile[32][33];
    int kt = blockIdx.x * 32, dt0 = blockIdx.y * 32, g = blockIdx.z;
    const float* W = g ? W2 : W1;
    int tx = threadIdx.x & 31, ty = threadIdx.x >> 5;  // ty 0..7
#pragma unroll
    for (int i = 0; i < 4; ++i) {
        int r = ty + i * 8;
        tile[r][tx] = W[(size_t)(kt + r) * DA + dt0 + tx];
    }
    __syncthreads();
#pragma unroll
    for (int i = 0; i < 4; ++i) {
        int r = ty + i * 8;                 // d within tile
        int d = dt0 + r, k = kt + tx;       // value = W[k][d]
        int dtI = d >> 6, col = d & 63, ktL = k >> 6, kin = k & 63;
        int slot = (kin >> 3) ^ (col & 7), e = kin & 7;
        size_t off = ((((size_t)dtI * 16 + ktL) * 2 + g) * 64 + col) * 64 + slot * 8 + e;
        WtImg[off] = f2bf(tile[tx][r]);
    }
}

// ---------------------------------------------------------------------------
// Kernel 2 v2: qproj[g][b][d] = bias + sum_k q[b][k]*Wg[1024+k][d]
// k-split 8-way: grid (DA/32, B, 2g) = 512 blocks, block 256 = 32 d x 8 ksub.
// q staged in LDS; serial chain 32 iters; LDS reduce of 8 partials.
// ---------------------------------------------------------------------------
__global__ void qproj_kernel(const float* __restrict__ q,
                             const float* __restrict__ W1, const float* __restrict__ b1,
                             const float* __restrict__ W2, const float* __restrict__ b2,
                             float* __restrict__ qp) {
    __shared__ float qs[DQ];        // 4 KB
    __shared__ float red[8][33];
    int b = blockIdx.y, g = blockIdx.z;
    int t = threadIdx.x;
    const float* W = g ? W2 : W1;
    const float* bias = g ? b2 : b1;
    for (int i = t; i < DQ / 4; i += 256)
        *(float4*)(&qs[i * 4]) = *(const float4*)(q + (size_t)b * DQ + (size_t)i * 4);
    __syncthreads();
    int dl = t & 31, ks = t >> 5;
    int d = blockIdx.x * 32 + dl;
    float acc = 0.f;
    int k0 = ks * 128;
#pragma unroll 4
    for (int i = 0; i < 32; ++i) {
        int k = k0 + i * 4;
        float4 q4 = *(const float4*)(&qs[k]);
        acc += q4.x * W[(size_t)(DF + k + 0) * DA + d];
        acc += q4.y * W[(size_t)(DF + k + 1) * DA + d];
        acc += q4.z * W[(size_t)(DF + k + 2) * DA + d];
        acc += q4.w * W[(size_t)(DF + k + 3) * DA + d];
    }
    red[ks][dl] = acc;
    __syncthreads();
    if (ks == 0) {
        float s = bias[d];
#pragma unroll
        for (int j = 0; j < 8; ++j) s += red[j][dl];
        qp[((size_t)g * B_ + b) * DA + d] = s;
    }
}

// ---------------------------------------------------------------------------
// Kernel 3: fused GEMM + gated-tanh + score reduce (UNCHANGED from round 4).
// ---------------------------------------------------------------------------
#define BM 128
#define BK 64

__global__ __launch_bounds__(256, 3) void gemm_score_kernel(
        const float* __restrict__ key, const unsigned short* __restrict__ WtImg,
        const float* __restrict__ qp, const float* __restrict__ w_a,
        float* __restrict__ scores_part) {
    __shared__ unsigned short Alds[BM * 64];          // 16 KB, 128B rows, XOR-swz
    __shared__ unsigned short Blds[2][2 * 64 * 64];   // 2 x 16 KB double buffer
    __shared__ float sred[BM][2];

    int p = blockIdx.x;
    int xcd = p & 7;
    int q = p >> 3;
    int gidx = xcd * 64 + (q >> 3);
    int dt = q & 7;
    int b = gidx >> 5;
    int mt = gidx & 31;

    int t = threadIdx.x;
    int w = t >> 6, l = t & 63;
    int jj = l & 15, g2 = l >> 4;
    int wr = (w >> 1) * 64;
    int wc = (w & 1) * 32;

    const float* Abase = key + ((size_t)b * N_ + (size_t)mt * BM) * DF;
    const unsigned short* Bsrc = WtImg + (size_t)dt * 16 * 8192;

    f32x4 acc[2][4][2];
#pragma unroll
    for (int g = 0; g < 2; ++g)
#pragma unroll
        for (int mi = 0; mi < 4; ++mi)
#pragma unroll
            for (int fc = 0; fc < 2; ++fc) acc[g][mi][fc] = (f32x4)0.f;

    int tr = t >> 4;
    int tcf = (t & 15) * 4;
    int aslot = (t & 15) >> 1;
    int ahalf = (t & 1) * 4;

    float4 areg[8];

#pragma unroll
    for (int i = 0; i < 4; ++i) {
        int c = w * 4 + i;
        gload_lds16(Bsrc + (size_t)c * 512 + l * 8, (char*)&Blds[0][0] + c * 1024);
    }
#pragma unroll
    for (int j = 0; j < 8; ++j)
        areg[j] = *(const float4*)(Abase + (size_t)(j * 16 + tr) * DF + tcf);

    for (int kt = 0; kt < DF / BK; ++kt) {
        int cur = kt & 1;
#pragma unroll
        for (int j = 0; j < 8; ++j) {
            int row = j * 16 + tr;
            ushort4 h;
            h.x = f2bf(areg[j].x); h.y = f2bf(areg[j].y);
            h.z = f2bf(areg[j].z); h.w = f2bf(areg[j].w);
            *(ushort4*)(&Alds[row * 64 + ((aslot ^ (tr & 7)) * 8) + ahalf]) = h;
        }
        if (kt < DF / BK - 1) {
            const unsigned short* src = Bsrc + (size_t)(kt + 1) * 8192;
#pragma unroll
            for (int i = 0; i < 4; ++i) {
                int c = w * 4 + i;
                gload_lds16(src + (size_t)c * 512 + l * 8, (char*)&Blds[cur ^ 1][0] + c * 1024);
            }
            int k0 = (kt + 1) * BK;
#pragma unroll
            for (int j = 0; j < 8; ++j)
                areg[j] = *(const float4*)(Abase + (size_t)(j * 16 + tr) * DF + k0 + tcf);
        }
        asm volatile("s_waitcnt lgkmcnt(0)" ::: "memory");
        __builtin_amdgcn_s_barrier();
        __builtin_amdgcn_sched_barrier(0);
#pragma unroll
        for (int kk = 0; kk < 2; ++kk) {
            short8v af[4], bfr[2][2];
            int ps = ((kk * 4 + g2) ^ (jj & 7)) * 8;
#pragma unroll
            for (int mi = 0; mi < 4; ++mi)
                af[mi] = *(const short8v*)(&Alds[(wr + mi * 16 + jj) * 64 + ps]);
#pragma unroll
            for (int g = 0; g < 2; ++g)
#pragma unroll
                for (int fc = 0; fc < 2; ++fc)
                    bfr[g][fc] = *(const short8v*)(&Blds[cur][(g * 64 + wc + fc * 16 + jj) * 64 + ps]);
#pragma unroll
            for (int g = 0; g < 2; ++g)
#pragma unroll
                for (int mi = 0; mi < 4; ++mi)
#pragma unroll
                    for (int fc = 0; fc < 2; ++fc)
                        acc[g][mi][fc] = __builtin_amdgcn_mfma_f32_16x16x32_bf16(
                            af[mi], bfr[g][fc], acc[g][mi][fc], 0, 0, 0);
        }
        __builtin_amdgcn_sched_barrier(0);
        __builtin_amdgcn_s_barrier();
    }

    const float* qp1b = qp + (size_t)b * DA;
    const float* qp2b = qp + ((size_t)B_ + b) * DA;
#pragma unroll
    for (int mi = 0; mi < 4; ++mi) {
        float s0 = 0.f, s1 = 0.f, s2 = 0.f, s3 = 0.f;
#pragma unroll
        for (int fc = 0; fc < 2; ++fc) {
            int col = dt * 64 + wc + fc * 16 + jj;
            float q1 = qp1b[col], q2 = qp2b[col], wa = w_a[col];
#pragma unroll
            for (int r = 0; r < 4; ++r) {
                float p1 = acc[0][mi][fc][r] + q1;
                float p2 = acc[1][mi][fc][r] + q2;
                float ax = fabsf(p1);
                float e = __expf(-2.f * ax);
                float th = __builtin_copysignf((1.f - e) / (1.f + e), p1);
                float sg = 1.f / (1.f + __expf(-p2));
                float h = th * sg * wa;
                if (r == 0) s0 += h; else if (r == 1) s1 += h; else if (r == 2) s2 += h; else s3 += h;
            }
        }
#pragma unroll
        for (int off = 1; off < 16; off <<= 1) {
            s0 += __shfl_xor(s0, off);
            s1 += __shfl_xor(s1, off);
            s2 += __shfl_xor(s2, off);
            s3 += __shfl_xor(s3, off);
        }
        float v = (jj == 0) ? s0 : (jj == 1) ? s1 : (jj == 2) ? s2 : s3;
        if (jj < 4) sred[wr + mi * 16 + g2 * 4 + jj][w & 1] = v;
    }
    __syncthreads();
    if (t < BM) {
        scores_part[((size_t)b * N_ + (size_t)mt * BM + t) * NDT + dt] = sred[t][0] + sred[t][1];
    }
}

// ---------------------------------------------------------------------------
// Kernel 4 v2: per-batch masked softmax. grid 16, block 1024 (16 waves),
// 4 rows per thread.
// ---------------------------------------------------------------------------
__global__ __launch_bounds__(1024) void softmax_kernel(
        const float* __restrict__ scores_part,
        const int* __restrict__ mask,
        float* __restrict__ attn_out) {
    int b = blockIdx.x;
    int t = threadIdx.x;
    __shared__ float wred[16];

    float vals[4];
    float mx = -3.0e38f;
#pragma unroll
    for (int i = 0; i < 4; ++i) {
        int n = t + 1024 * i;
        const float4* sp = (const float4*)(scores_part + ((size_t)b * N_ + n) * NDT);
        float4 u = sp[0], v = sp[1];
        float s = ((u.x + u.y) + (u.z + u.w)) + ((v.x + v.y) + (v.z + v.w));
        if (mask[(size_t)b * N_ + n] == 0) s = -1e18f;
        vals[i] = s;
        mx = fmaxf(mx, s);
    }
#pragma unroll
    for (int off = 32; off >= 1; off >>= 1) mx = fmaxf(mx, __shfl_xor(mx, off));
    if ((t & 63) == 0) wred[t >> 6] = mx;
    __syncthreads();
    mx = wred[0];
#pragma unroll
    for (int j = 1; j < 16; ++j) mx = fmaxf(mx, wred[j]);
    __syncthreads();

    float sum = 0.f;
#pragma unroll
    for (int i = 0; i < 4; ++i) {
        float e = __expf(vals[i] - mx);
        vals[i] = e;
        sum += e;
    }
#pragma unroll
    for (int off = 32; off >= 1; off >>= 1) sum += __shfl_xor(sum, off);
    if ((t & 63) == 0) wred[t >> 6] = sum;
    __syncthreads();
    sum = wred[0];
#pragma unroll
    for (int j = 1; j < 16; ++j) sum += wred[j];
    float inv = 1.f / sum;
#pragma unroll
    for (int i = 0; i < 4; ++i) attn_out[(size_t)b * N_ + t + 1024 * i] = vals[i] * inv;
}

// ---------------------------------------------------------------------------
// Kernel 5: context partials (unchanged)
// ---------------------------------------------------------------------------
__global__ void ctx_part_kernel(const float* __restrict__ attn,
                                const float* __restrict__ value,
                                float* __restrict__ ctx_part) {
    int ns = blockIdx.x, b = blockIdx.y, t = threadIdx.x;
    const int NCH = N_ / NS;  // 128
    const float* vb = value + ((size_t)b * N_ + (size_t)ns * NCH) * DF + t * 4;
    const float* ab = attn + (size_t)b * N_ + ns * NCH;
    float4 acc = {0.f, 0.f, 0.f, 0.f};
#pragma unroll 4
    for (int i = 0; i < NCH; ++i) {
        float a = ab[i];
        float4 v = *(const float4*)(vb + (size_t)i * DF);
        acc.x += a * v.x; acc.y += a * v.y; acc.z += a * v.z; acc.w += a * v.w;
    }
    *(float4*)(ctx_part + ((size_t)b * NS + ns) * DF + t * 4) = acc;
}

// ---------------------------------------------------------------------------
// Kernel 6: reduce partials -> context (unchanged)
// ---------------------------------------------------------------------------
__global__ void ctx_reduce_kernel(const float* __restrict__ ctx_part,
                                  float* __restrict__ ctx_out) {
    int b = blockIdx.x, t = threadIdx.x;
    float4 acc = {0.f, 0.f, 0.f, 0.f};
#pragma unroll
    for (int j = 0; j < NS; ++j) {
        float4 v = *(const float4*)(ctx_part + ((size_t)b * NS + j) * DF + t * 4);
        acc.x += v.x; acc.y += v.y; acc.z += v.z; acc.w += v.w;
    }
    *(float4*)(ctx_out + (size_t)b * DF + t * 4) = acc;
}

// ---------------------------------------------------------------------------
extern "C" void kernel_launch(void* const* d_in, const int* in_sizes, int n_in,
                              void* d_out, int out_size, void* d_ws, size_t ws_size,
                              hipStream_t stream) {
    const float* query = (const float*)d_in[0];
    const float* key   = (const float*)d_in[1];
    const float* value = (const float*)d_in[2];
    const int*   mask  = (const int*)d_in[3];
    const float* W1    = (const float*)d_in[4];
    const float* b1    = (const float*)d_in[5];
    const float* W2    = (const float*)d_in[6];
    const float* b2    = (const float*)d_in[7];
    const float* w_a   = (const float*)d_in[8];

    float* attn_out = (float*)d_out;                    // [16,4096]
    float* ctx_out  = (float*)d_out + (size_t)B_ * N_;  // [16,1024]

    char* ws = (char*)d_ws;
    unsigned short* WtImg = (unsigned short*)ws;                      // 2 MB
    size_t off = (size_t)2 * DA * DF * sizeof(unsigned short);
    float* qp = (float*)(ws + off);                                   // 64 KB
    off += (size_t)2 * B_ * DA * sizeof(float);
    float* scores_part = (float*)(ws + off);                          // 2 MB
    off += (size_t)B_ * N_ * NDT * sizeof(float);
    float* ctx_part = (float*)(ws + off);                             // 2 MB
    off += (size_t)B_ * NS * DF * sizeof(float);

    wconv_kernel<<<dim3(DF / 32, DA / 32, 2), 256, 0, stream>>>(W1, W2, WtImg);
    qproj_kernel<<<dim3(DA / 32, B_, 2), 256, 0, stream>>>(query, W1, b1, W2, b2, qp);
    gemm_score_kernel<<<dim3(B_ * (N_ / BM) * NDT), 256, 0, stream>>>(key, WtImg, qp, w_a, scores_part);
    softmax_kernel<<<dim3(B_), 1024, 0, stream>>>(scores_part, mask, attn_out);
    ctx_part_kernel<<<dim3(NS, B_), 256, 0, stream>>>(attn_out, value, ctx_part);
    ctx_reduce_kernel<<<dim3(B_), 256, 0, stream>>>(ctx_part, ctx_out);
}